// Round 1
// baseline (110.941 us; speedup 1.0000x reference)
//
#include <hip/hip_runtime.h>
#include <hip/hip_bf16.h>

typedef __attribute__((ext_vector_type(8))) short short8;
typedef __attribute__((ext_vector_type(4))) float floatx4;

#define B_ROWS 8192
#define DIM 128

// ---------------- zero Z ----------------
__global__ void kzero(float* __restrict__ Z) {
    int i = blockIdx.x * 256 + threadIdx.x;
    if (i < B_ROWS) Z[i] = 0.f;
}

// ------------- normalize rows, cast to bf16 -------------
// one wave per row; lane loads 2 floats
__global__ void knorm(const float* __restrict__ X, __hip_bfloat16* __restrict__ XN) {
    const int wid = threadIdx.x >> 6;
    const int lane = threadIdx.x & 63;
    const int row = blockIdx.x * 4 + wid;
    const float2 v = *reinterpret_cast<const float2*>(X + row * DIM + lane * 2);
    float ss = v.x * v.x + v.y * v.y;
    #pragma unroll
    for (int m = 1; m < 64; m <<= 1) ss += __shfl_xor(ss, m, 64);
    const float rn = ss > 0.f ? rsqrtf(ss) : 0.f;
    __hip_bfloat162 hv = __float22bfloat162_rn(make_float2(v.x * rn, v.y * rn));
    *reinterpret_cast<__hip_bfloat162*>(XN + row * DIM + lane * 2) = hv;
}

// ------------- exact fp32 pair similarities S[2p, 2p+1] -------------
__global__ void kpairs(const float* __restrict__ X, float* __restrict__ pairT) {
    const int wid = threadIdx.x >> 6;
    const int lane = threadIdx.x & 63;
    const int p = blockIdx.x * 4 + wid;
    if (p >= (B_ROWS / 2 - 1)) return;  // 4095 pairs
    const float2 a = *reinterpret_cast<const float2*>(X + (2 * p) * DIM + lane * 2);
    const float2 b = *reinterpret_cast<const float2*>(X + (2 * p + 1) * DIM + lane * 2);
    float dxy = a.x * b.x + a.y * b.y;
    float dxx = a.x * a.x + a.y * a.y;
    float dyy = b.x * b.x + b.y * b.y;
    #pragma unroll
    for (int m = 1; m < 64; m <<= 1) {
        dxy += __shfl_xor(dxy, m, 64);
        dxx += __shfl_xor(dxx, m, 64);
        dyy += __shfl_xor(dyy, m, 64);
    }
    if (lane == 0)
        pairT[p] = dxy / fmaxf(sqrtf(dxx) * sqrtf(dyy), 1e-8f);
}

// ------------- main: S-tile MFMA + exp + row-sum into Z -------------
// grid (64, 64); block 256 = 4 waves; each block does a 128x128 tile of S.
// K = 128 staged entirely in LDS (A tile rows rb, B tile rows cb; S = Xn Xn^T).
#define GLOAD_LDS16(gp, lp)                                                     \
    __builtin_amdgcn_global_load_lds(                                           \
        (const __attribute__((address_space(1))) void*)(gp),                    \
        (__attribute__((address_space(3))) void*)(lp), 16, 0, 0)

__global__ void __launch_bounds__(256) kgemm(const __hip_bfloat16* __restrict__ XN,
                                             float* __restrict__ Z) {
    __shared__ __hip_bfloat16 As[128 * 128];
    __shared__ __hip_bfloat16 Bs[128 * 128];

    const int tid = threadIdx.x;
    const int wid = tid >> 6;
    const int lane = tid & 63;
    const int rb = blockIdx.y;
    const int cb = blockIdx.x;
    const int lr = lane & 15;   // fragment row (A) / col (B) / D col
    const int lk = lane >> 4;   // k-group / D row group

    // ---- stage both 32KB tiles (contiguous row blocks of XN) ----
    const __hip_bfloat16* ga = XN + rb * 128 * DIM;
    const __hip_bfloat16* gb = XN + cb * 128 * DIM;
    #pragma unroll
    for (int it = 0; it < 8; ++it) {
        const int woff = it * 2048 + wid * 512;  // wave-uniform element offset
        GLOAD_LDS16(ga + woff + lane * 8, &As[woff]);
        GLOAD_LDS16(gb + woff + lane * 8, &Bs[woff]);
    }
    __syncthreads();

    const int wr = wid >> 1;  // wave row quadrant (64 rows)
    const int wc = wid & 1;   // wave col quadrant (64 cols)

    floatx4 acc[4][4];
    #pragma unroll
    for (int m = 0; m < 4; ++m)
        #pragma unroll
        for (int n = 0; n < 4; ++n)
            acc[m][n] = floatx4{0.f, 0.f, 0.f, 0.f};

    #pragma unroll
    for (int kk = 0; kk < 4; ++kk) {
        short8 a[4], b[4];
        #pragma unroll
        for (int m = 0; m < 4; ++m)
            a[m] = *reinterpret_cast<const short8*>(
                &As[(wr * 64 + m * 16 + lr) * DIM + kk * 32 + lk * 8]);
        #pragma unroll
        for (int n = 0; n < 4; ++n)
            b[n] = *reinterpret_cast<const short8*>(
                &Bs[(wc * 64 + n * 16 + lr) * DIM + kk * 32 + lk * 8]);
        #pragma unroll
        for (int m = 0; m < 4; ++m)
            #pragma unroll
            for (int n = 0; n < 4; ++n)
                acc[m][n] = __builtin_amdgcn_mfma_f32_16x16x32_bf16(
                    a[m], b[n], acc[m][n], 0, 0, 0);
    }

    // ---- epilogue: exp, exclude diagonal, row-sum, atomic into Z ----
    const int rbase = rb * 128 + wr * 64;
    const int cbase = cb * 128 + wc * 64;
    #pragma unroll
    for (int m = 0; m < 4; ++m) {
        float rp[4] = {0.f, 0.f, 0.f, 0.f};
        #pragma unroll
        for (int n = 0; n < 4; ++n) {
            #pragma unroll
            for (int r = 0; r < 4; ++r) {
                const int R = rbase + m * 16 + lk * 4 + r;
                const int C = cbase + n * 16 + lr;
                const float s = acc[m][n][r];
                rp[r] += (R == C) ? 0.f : __expf(s);
            }
        }
        #pragma unroll
        for (int r = 0; r < 4; ++r) {
            float v = rp[r];
            v += __shfl_xor(v, 1, 64);
            v += __shfl_xor(v, 2, 64);
            v += __shfl_xor(v, 4, 64);
            v += __shfl_xor(v, 8, 64);
            if (lr == 0)
                atomicAdd(&Z[rbase + m * 16 + lk * 4 + r], v);
        }
    }
}

// ------------- final: loss = (sum logZ[0..8189] - 2*sum pairT) / B -------------
__global__ void kfinal(const float* __restrict__ Z, const float* __restrict__ pairT,
                       float* __restrict__ out) {
    float s = 0.f;
    for (int r = threadIdx.x; r < B_ROWS - 2; r += 1024) s += logf(Z[r]);
    for (int p = threadIdx.x; p < (B_ROWS / 2 - 1); p += 1024) s -= 2.f * pairT[p];
    #pragma unroll
    for (int m = 1; m < 64; m <<= 1) s += __shfl_xor(s, m, 64);
    __shared__ float red[16];
    const int wid = threadIdx.x >> 6;
    const int lane = threadIdx.x & 63;
    if (lane == 0) red[wid] = s;
    __syncthreads();
    if (threadIdx.x == 0) {
        float t = 0.f;
        #pragma unroll
        for (int i = 0; i < 16; ++i) t += red[i];
        out[0] = t / (float)B_ROWS;
    }
}

extern "C" void kernel_launch(void* const* d_in, const int* in_sizes, int n_in,
                              void* d_out, int out_size, void* d_ws, size_t ws_size,
                              hipStream_t stream) {
    (void)in_sizes; (void)n_in; (void)out_size; (void)ws_size;
    const float* X = (const float*)d_in[0];
    float* out = (float*)d_out;
    char* ws = (char*)d_ws;
    float* Z = (float*)ws;                                  // 8192 f32
    float* pairT = (float*)(ws + B_ROWS * 4);               // 4096 f32
    __hip_bfloat16* XN = (__hip_bfloat16*)(ws + B_ROWS * 4 + 4096 * 4);  // 8192*128 bf16

    kzero<<<32, 256, 0, stream>>>(Z);
    knorm<<<2048, 256, 0, stream>>>(X, XN);
    kpairs<<<1024, 256, 0, stream>>>(X, pairT);
    kgemm<<<dim3(64, 64), 256, 0, stream>>>(XN, Z);
    kfinal<<<1, 1024, 0, stream>>>(Z, pairT, out);
}

// Round 2
// 47.578 us; speedup vs baseline: 2.3318x; 2.3318x over previous
//
#include <hip/hip_runtime.h>
#include <hip/hip_bf16.h>

typedef __attribute__((ext_vector_type(8))) short short8;
typedef __attribute__((ext_vector_type(4))) float floatx4;

#define B_ROWS 8192
#define DIM 128
#define NPAIR (B_ROWS / 2 - 1)  // 4095

#define GLOAD_LDS16(gp, lp)                                                     \
    __builtin_amdgcn_global_load_lds(                                           \
        (const __attribute__((address_space(1))) void*)(gp),                    \
        (__attribute__((address_space(3))) void*)(lp), 16, 0, 0)

// ---------------- zero Z (fallback path only) ----------------
__global__ void kzero(float* __restrict__ Z) {
    int i = blockIdx.x * 256 + threadIdx.x;
    if (i < B_ROWS) Z[i] = 0.f;
}

// ------------- normalize rows, cast to bf16; zero out[0] -------------
__global__ void knorm(const float* __restrict__ X, __hip_bfloat16* __restrict__ XN,
                      float* __restrict__ out) {
    const int wid = threadIdx.x >> 6;
    const int lane = threadIdx.x & 63;
    const int row = blockIdx.x * 4 + wid;
    const float2 v = *reinterpret_cast<const float2*>(X + row * DIM + lane * 2);
    float ss = v.x * v.x + v.y * v.y;
    #pragma unroll
    for (int m = 1; m < 64; m <<= 1) ss += __shfl_xor(ss, m, 64);
    const float rn = ss > 0.f ? rsqrtf(ss) : 0.f;
    __hip_bfloat162 hv = __float22bfloat162_rn(make_float2(v.x * rn, v.y * rn));
    *reinterpret_cast<__hip_bfloat162*>(XN + row * DIM + lane * 2) = hv;
    if (blockIdx.x == 0 && threadIdx.x == 0) out[0] = 0.f;
}

// ------------- exact fp32 pair similarities S[2p, 2p+1] -------------
__global__ void kpairs(const float* __restrict__ X, float* __restrict__ pairT) {
    const int wid = threadIdx.x >> 6;
    const int lane = threadIdx.x & 63;
    const int p = blockIdx.x * 4 + wid;
    if (p >= NPAIR) return;
    const float2 a = *reinterpret_cast<const float2*>(X + (2 * p) * DIM + lane * 2);
    const float2 b = *reinterpret_cast<const float2*>(X + (2 * p + 1) * DIM + lane * 2);
    float dxy = a.x * b.x + a.y * b.y;
    float dxx = a.x * a.x + a.y * a.y;
    float dyy = b.x * b.x + b.y * b.y;
    #pragma unroll
    for (int m = 1; m < 64; m <<= 1) {
        dxy += __shfl_xor(dxy, m, 64);
        dxx += __shfl_xor(dxx, m, 64);
        dyy += __shfl_xor(dyy, m, 64);
    }
    if (lane == 0)
        pairT[p] = dxy / fmaxf(sqrtf(dxx) * sqrtf(dyy), 1e-8f);
}

// ------------- main: upper-triangle S tiles, MFMA + exp + row/col sums -------------
// grid = 2080 blocks (64*65/2 triangle tiles), block 256 = 4 waves.
// USEP: plain stores into P[128][8192] (unique writer per slot). else atomics into Z.
template <bool USEP>
__global__ void __launch_bounds__(256) kgemm(const __hip_bfloat16* __restrict__ XN,
                                             float* __restrict__ ZP) {
    __shared__ __hip_bfloat16 As[128 * 128];
    __shared__ __hip_bfloat16 Bs[128 * 128];

    const int tid = threadIdx.x;
    const int wid = tid >> 6;
    const int lane = tid & 63;
    const int lr = lane & 15;
    const int lk = lane >> 4;

    // triangular decode blockIdx.x -> (rb <= cb)
    const int t = blockIdx.x;
    int cb = (int)((sqrtf(8.f * (float)t + 1.f) - 1.f) * 0.5f);
    while ((cb + 1) * (cb + 2) / 2 <= t) ++cb;
    while (cb * (cb + 1) / 2 > t) --cb;
    const int rb = t - cb * (cb + 1) / 2;
    const bool diag = (rb == cb);

    // ---- stage tiles; source pre-swizzled so swizzled ds_read is conflict-free ----
    const __hip_bfloat16* ga = XN + rb * 128 * DIM;
    const __hip_bfloat16* gb = XN + cb * 128 * DIM;
    #pragma unroll
    for (int it = 0; it < 8; ++it) {
        const int woff = it * 2048 + wid * 512;  // wave-uniform element offset
        const int g = woff + lane * 8;
        const int src = (g & ~127) | ((g & 127) ^ (((g >> 7) & 7) << 3));
        GLOAD_LDS16(ga + src, &As[woff]);
        if (!diag) GLOAD_LDS16(gb + src, &Bs[woff]);
    }
    __syncthreads();
    const __hip_bfloat16* Bp = diag ? As : Bs;

    const int wr = wid >> 1;  // wave row quadrant (64 rows)
    const int wc = wid & 1;   // wave col quadrant (64 cols)

    floatx4 acc[4][4];
    #pragma unroll
    for (int m = 0; m < 4; ++m)
        #pragma unroll
        for (int n = 0; n < 4; ++n)
            acc[m][n] = floatx4{0.f, 0.f, 0.f, 0.f};

    #pragma unroll
    for (int kk = 0; kk < 4; ++kk) {
        short8 a[4], b[4];
        #pragma unroll
        for (int m = 0; m < 4; ++m) {
            const int row = wr * 64 + m * 16 + lr;
            const int col = (kk * 32 + lk * 8) ^ ((row & 7) << 3);
            a[m] = *reinterpret_cast<const short8*>(&As[row * DIM + col]);
        }
        #pragma unroll
        for (int n = 0; n < 4; ++n) {
            const int row = wc * 64 + n * 16 + lr;
            const int col = (kk * 32 + lk * 8) ^ ((row & 7) << 3);
            b[n] = *reinterpret_cast<const short8*>(&Bp[row * DIM + col]);
        }
        #pragma unroll
        for (int m = 0; m < 4; ++m)
            #pragma unroll
            for (int n = 0; n < 4; ++n)
                acc[m][n] = __builtin_amdgcn_mfma_f32_16x16x32_bf16(
                    a[m], b[n], acc[m][n], 0, 0, 0);
    }

    // ---- epilogue: exp once, accumulate row sums and col sums ----
    const int rbase = rb * 128 + wr * 64;
    const int cbase = cb * 128 + wc * 64;
    float rp[4][4];
    float cp[4] = {0.f, 0.f, 0.f, 0.f};
    #pragma unroll
    for (int m = 0; m < 4; ++m)
        #pragma unroll
        for (int r = 0; r < 4; ++r) rp[m][r] = 0.f;

    #pragma unroll
    for (int m = 0; m < 4; ++m)
        #pragma unroll
        for (int n = 0; n < 4; ++n)
            #pragma unroll
            for (int r = 0; r < 4; ++r) {
                const int R = rbase + m * 16 + lk * 4 + r;
                const int C = cbase + n * 16 + lr;
                float e = __expf(acc[m][n][r]);
                e = (R == C) ? 0.f : e;  // only possible on diag tiles
                rp[m][r] += e;
                cp[n] += e;
            }

    // row sums: reduce across lr (lanes sharing a D row)
    #pragma unroll
    for (int m = 0; m < 4; ++m)
        #pragma unroll
        for (int r = 0; r < 4; ++r) {
            float v = rp[m][r];
            v += __shfl_xor(v, 1, 64);
            v += __shfl_xor(v, 2, 64);
            v += __shfl_xor(v, 4, 64);
            v += __shfl_xor(v, 8, 64);
            if (lr == 0) {
                const int row = rbase + m * 16 + lk * 4 + r;
                if (USEP)
                    ZP[(cb * 2 + wc) * B_ROWS + row] = v;
                else
                    atomicAdd(&ZP[row], v);
            }
        }

    // col sums (transpose contribution): reduce across lk groups
    if (!diag) {
        #pragma unroll
        for (int n = 0; n < 4; ++n) {
            float v = cp[n];
            v += __shfl_xor(v, 16, 64);
            v += __shfl_xor(v, 32, 64);
            if (lane < 16) {
                const int col = cbase + n * 16 + lr;
                if (USEP)
                    ZP[(rb * 2 + wr) * B_ROWS + col] = v;
                else
                    atomicAdd(&ZP[col], v);
            }
        }
    }
}

// ------------- final (P path): Z[r] = sum_t P[t][r]; loss reduce -------------
__global__ void kfinalP(const float* __restrict__ P, const float* __restrict__ pairT,
                        float* __restrict__ out) {
    const int r = blockIdx.x * 256 + threadIdx.x;
    float s = 0.f;
    if (r < B_ROWS - 2) {
        float z = 0.f;
        #pragma unroll 8
        for (int tt = 0; tt < 128; ++tt) z += P[tt * B_ROWS + r];
        s = logf(z);
    }
    if (r < NPAIR) s -= 2.f * pairT[r];
    #pragma unroll
    for (int m = 1; m < 64; m <<= 1) s += __shfl_xor(s, m, 64);
    __shared__ float red[4];
    const int wid = threadIdx.x >> 6;
    const int lane = threadIdx.x & 63;
    if (lane == 0) red[wid] = s;
    __syncthreads();
    if (threadIdx.x == 0) {
        float tsum = red[0] + red[1] + red[2] + red[3];
        atomicAdd(out, tsum / (float)B_ROWS);
    }
}

// ------------- final (Z fallback path) -------------
__global__ void kfinalZ(const float* __restrict__ Z, const float* __restrict__ pairT,
                        float* __restrict__ out) {
    float s = 0.f;
    for (int r = threadIdx.x; r < B_ROWS - 2; r += 1024) s += logf(Z[r]);
    for (int p = threadIdx.x; p < NPAIR; p += 1024) s -= 2.f * pairT[p];
    #pragma unroll
    for (int m = 1; m < 64; m <<= 1) s += __shfl_xor(s, m, 64);
    __shared__ float red[16];
    const int wid = threadIdx.x >> 6;
    const int lane = threadIdx.x & 63;
    if (lane == 0) red[wid] = s;
    __syncthreads();
    if (threadIdx.x == 0) {
        float t = 0.f;
        #pragma unroll
        for (int i = 0; i < 16; ++i) t += red[i];
        out[0] = t / (float)B_ROWS;
    }
}

extern "C" void kernel_launch(void* const* d_in, const int* in_sizes, int n_in,
                              void* d_out, int out_size, void* d_ws, size_t ws_size,
                              hipStream_t stream) {
    (void)in_sizes; (void)n_in; (void)out_size;
    const float* X = (const float*)d_in[0];
    float* out = (float*)d_out;
    char* ws = (char*)d_ws;

    float* Z = (float*)ws;                                   // 32 KB
    float* pairT = (float*)(ws + 32768);                     // 16 KB
    __hip_bfloat16* XN = (__hip_bfloat16*)(ws + 49152);      // 2 MB
    float* P = (float*)(ws + 49152 + 2097152);               // 4 MB
    const size_t need = 49152 + 2097152 + (size_t)128 * B_ROWS * 4;
    const bool useP = ws_size >= need;

    knorm<<<2048, 256, 0, stream>>>(X, XN, out);
    kpairs<<<1024, 256, 0, stream>>>(X, pairT);
    if (useP) {
        kgemm<true><<<2080, 256, 0, stream>>>(XN, P);
        kfinalP<<<32, 256, 0, stream>>>(P, pairT, out);
    } else {
        kzero<<<32, 256, 0, stream>>>(Z);
        kgemm<false><<<2080, 256, 0, stream>>>(XN, Z);
        kfinalZ<<<1, 1024, 0, stream>>>(Z, pairT, out);
    }
}